// Round 2
// 572.875 us; speedup vs baseline: 1.0014x; 1.0014x over previous
//
#include <hip/hip_runtime.h>

// Problem constants (from reference):
//   B = 262144 rows, N = 64 features, P = 8 weight pairs
//   indices = 1 - eye(N)  =>  W[p,m,n] = (n==m) ? w[p,0] : w[p,1]
//   out[b, p*N+m] = x[b,m]*(w[p,0]-w[p,1]) + w[p,1]*sum_n x[b,n]
// Memory-bound: 64 MiB read + 512 MiB write = 576 MiB ideal traffic.
//
// Structure: no LDS, no barrier. The 16 lanes covering one row are always
// within one wave, so the row sum is a width-16 shfl_xor reduction. Each
// thread keeps its loaded float4 in registers and writes the 8 output
// float4s that depend on exactly those 4 x-values.
// 2048 blocks x 256 threads x 8 float4/thread covers B*N/4 = 4,194,304
// float4s exactly. 8 independent nt-loads issued up front per thread for
// MLP; 64 nt-stores with immediate offsets.
//
// NOTE: __builtin_nontemporal_load/store requires a NATIVE vector type —
// HIP's float4 (HIP_vector_type) is rejected. Use ext_vector_type(4).

typedef float f4 __attribute__((ext_vector_type(4)));

constexpr int BROWS   = 262144;
constexpr int N       = 64;
constexpr int P       = 8;
constexpr int THREADS = 256;
constexpr int BLOCKS  = 2048;   // 8 blocks/CU on 256 CUs -> 32 waves/CU
constexpr int UNROLL  = 8;
// BLOCKS * THREADS * UNROLL == BROWS * N / 4 exactly.
static_assert((long long)BLOCKS * THREADS * UNROLL ==
              (long long)BROWS * N / 4, "grid must tile x exactly");

__global__ __launch_bounds__(THREADS)
void pcl_kernel(const f4* __restrict__ x4,
                const float* __restrict__ w,
                f4* __restrict__ out4)
{
    // w is tiny and wave-uniform: compiler emits scalar loads, d/w1 live
    // in SGPRs.
    float d[P], w1[P];
    #pragma unroll
    for (int p = 0; p < P; ++p) {
        const float a = w[2 * p];
        const float b = w[2 * p + 1];
        d[p]  = a - b;
        w1[p] = b;
    }

    const int t = threadIdx.x;
    const long long base   = (long long)blockIdx.x * THREADS + t;
    constexpr long long STRIDE = (long long)BLOCKS * THREADS; // multiple of 16

    // Issue all 8 independent loads first (MLP).
    f4 v[UNROLL];
    #pragma unroll
    for (int k = 0; k < UNROLL; ++k)
        v[k] = __builtin_nontemporal_load(&x4[base + (long long)k * STRIDE]);

    #pragma unroll
    for (int k = 0; k < UNROLL; ++k) {
        const long long i = base + (long long)k * STRIDE; // global float4 idx
        // Row sum: 16 consecutive float4s form one row; i & 15 == lane & 15
        // because STRIDE and block offsets are multiples of 16. All 16
        // participants are in the same wave -> shfl, no LDS, no barrier.
        float s = v[k].x + v[k].y + v[k].z + v[k].w;
        s += __shfl_xor(s, 1, 16);
        s += __shfl_xor(s, 2, 16);
        s += __shfl_xor(s, 4, 16);
        s += __shfl_xor(s, 8, 16);

        const long long r  = i >> 4;        // row b
        const int       ms = (int)(i & 15); // float4 index within x row
        // out row has P*N/4 = 128 float4; this thread writes p*16 + ms.
        f4* op = out4 + r * 128 + ms;
        #pragma unroll
        for (int p = 0; p < P; ++p) {
            const float bb = w1[p] * s;
            f4 o;
            o.x = v[k].x * d[p] + bb;
            o.y = v[k].y * d[p] + bb;
            o.z = v[k].z * d[p] + bb;
            o.w = v[k].w * d[p] + bb;
            // p*16 f4 = 256 B -> folds into the 13-bit imm offset.
            __builtin_nontemporal_store(o, op + p * 16);
        }
    }
}

extern "C" void kernel_launch(void* const* d_in, const int* in_sizes, int n_in,
                              void* d_out, int out_size, void* d_ws, size_t ws_size,
                              hipStream_t stream)
{
    const f4* x = (const f4*)d_in[0];
    const float* w = (const float*)d_in[1];
    // d_in[2] (indices) is structurally 1 - eye(N); not needed at runtime.
    f4* out = (f4*)d_out;

    pcl_kernel<<<BLOCKS, THREADS, 0, stream>>>(x, w, out);
}